// Round 4
// baseline (530.550 us; speedup 1.0000x reference)
//
#include <hip/hip_runtime.h>
#include <math.h>

// Chamfer distance, N=2, D=3 fp32 — grid-pruned exact nearest neighbor.
// r3 diagnosis: brute force is at ~75% of the MEASURED fp32 VALU ceiling
// (m07: 103 TF); its floor is ~40us. Switch to a 32^3 uniform grid with
// expanding-shell exact NN search: ~25x fewer candidate pairs.
// Exactness: after scanning Chebyshev shells <= s, any unscanned point has
// true distance >= s*h (clamping is a projection => non-expansive), so
// terminating when best <= (s*h)^2 never misses the true min. The candidate
// SET is deterministic (termination depends only on set-wise min), so the
// result is bit-stable even though counting-sort ranks come from atomicAdd.
// Fallback: if ws_size < needed, run the r2 brute-force path (~59us).

#define G 32
#define NC (G * G * G)
#define HLO -4.5f
#define HSPAN 9.0f
#define QBLK 64
#define P2A_BLOCKS 6
#define P2A_PAD 8

__device__ __forceinline__ int cell_coord(float x) {
    int i = (int)floorf((x - HLO) * ((float)G / HSPAN));
    return min(max(i, 0), G - 1);
}

// ---------------- grid path ----------------

__global__ __launch_bounds__(256) void grid_build(
    const float* __restrict__ c1, const float* __restrict__ c2,
    int P1, int P2, unsigned* __restrict__ hist,
    unsigned* __restrict__ cellid, unsigned* __restrict__ rank) {
    const int set = blockIdx.y;           // n*2 + cloud
    const int n = set >> 1, cl = set & 1;
    const int P = cl ? P2 : P1;
    const int i = blockIdx.x * 256 + threadIdx.x;
    if (i >= P) return;
    const float* p = (cl ? c2 + (size_t)n * P2 * 3 : c1 + (size_t)n * P1 * 3) + (size_t)i * 3;
    const int ix = cell_coord(p[0]), iy = cell_coord(p[1]), iz = cell_coord(p[2]);
    const unsigned c = ((unsigned)iz * G + iy) * G + ix;
    const unsigned r = atomicAdd(&hist[(size_t)set * NC + c], 1u);
    const int poff = n * (P1 + P2) + (cl ? P1 : 0);
    cellid[poff + i] = c;
    rank[poff + i] = r;
}

__global__ __launch_bounds__(1024) void grid_scan(
    const unsigned* __restrict__ hist, unsigned* __restrict__ starts) {
    const int set = blockIdx.x;
    const unsigned* h = hist + (size_t)set * NC;
    unsigned* st = starts + (size_t)set * NC;
    const int t = threadIdx.x;
    const int CH = NC / 1024;             // 32
    unsigned s = 0;
    for (int k = 0; k < CH; ++k) s += h[t * CH + k];
    __shared__ unsigned sd[1024];
    sd[t] = s;
    __syncthreads();
    for (int off = 1; off < 1024; off <<= 1) {
        unsigned v = (t >= off) ? sd[t - off] : 0u;
        __syncthreads();
        sd[t] += v;
        __syncthreads();
    }
    unsigned run = (t == 0) ? 0u : sd[t - 1];
    for (int k = 0; k < CH; ++k) {
        st[t * CH + k] = run;
        run += h[t * CH + k];
    }
}

__global__ __launch_bounds__(256) void grid_scatter(
    const float* __restrict__ c1, const float* __restrict__ c2,
    int P1, int P2, const unsigned* __restrict__ starts,
    const unsigned* __restrict__ cellid, const unsigned* __restrict__ rank,
    float4* __restrict__ sorted, unsigned* __restrict__ sidx) {
    const int set = blockIdx.y;
    const int n = set >> 1, cl = set & 1;
    const int P = cl ? P2 : P1;
    const int i = blockIdx.x * 256 + threadIdx.x;
    if (i >= P) return;
    const float* p = (cl ? c2 + (size_t)n * P2 * 3 : c1 + (size_t)n * P1 * 3) + (size_t)i * 3;
    const float x = p[0], y = p[1], z = p[2];
    const int poff = n * (P1 + P2) + (cl ? P1 : 0);
    const unsigned c = cellid[poff + i];
    const unsigned pos = starts[(size_t)set * NC + c] + rank[poff + i];
    sorted[poff + pos] = make_float4(-2.f * x, -2.f * y, -2.f * z,
                                     fmaf(x, x, fmaf(y, y, z * z)));
    sidx[poff + pos] = i;
}

__global__ __launch_bounds__(QBLK) void grid_query(
    int P1, int P2, const unsigned* __restrict__ hist,
    const unsigned* __restrict__ starts, const float4* __restrict__ sorted,
    const unsigned* __restrict__ sidx, float* __restrict__ mk) {
    const int zz = blockIdx.y;            // n*2 + dir
    const int n = zz >> 1, dir = zz & 1;
    const int ts = n * 2 + (dir ? 0 : 1); // target set
    const int Pq = dir ? P2 : P1;
    const int qoff = n * (P1 + P2) + (dir ? P1 : 0);
    const int toff = n * (P1 + P2) + (dir ? 0 : P1);
    const int qi = blockIdx.x * QBLK + threadIdx.x;
    if (qi >= Pq) return;

    const float4 q = sorted[qoff + qi];   // sorted order -> wave-coherent cells
    const unsigned orig = sidx[qoff + qi];
    const float ax = -0.5f * q.x, ay = -0.5f * q.y, az = -0.5f * q.z, qw = q.w;
    const int cx = cell_coord(ax), cy = cell_coord(ay), cz = cell_coord(az);
    const unsigned* tst = starts + (size_t)ts * NC;
    const unsigned* tcnt = hist + (size_t)ts * NC;
    const float4* T = sorted + toff;
    const float h = HSPAN / (float)G;     // 0.28125 exact

    float best = INFINITY;                // partial: ||b||^2 - 2 a.b
    for (int s = 0; s < G; ++s) {
        for (int dz = -s; dz <= s; ++dz) {
            const int z2 = cz + dz;
            if ((unsigned)z2 >= G) continue;
            const bool zface = (dz == -s) || (dz == s);
            for (int dy = -s; dy <= s; ++dy) {
                const int y2 = cy + dy;
                if ((unsigned)y2 >= G) continue;
                const bool face = zface || dy == -s || dy == s;
                const int xstep = (face || s == 0) ? 1 : 2 * s;
                for (int x2 = cx - s; x2 <= cx + s; x2 += xstep) {
                    if ((unsigned)x2 >= G) continue;
                    const int c = (z2 * G + y2) * G + x2;
                    const unsigned st = tst[c];
                    const unsigned cnt = tcnt[c];
                    for (unsigned k = 0; k < cnt; ++k) {
                        const float4 b = T[st + k];
                        best = fminf(best,
                            fmaf(ax, b.x, fmaf(ay, b.y, fmaf(az, b.z, b.w))));
                    }
                }
            }
        }
        const float bound = (float)s * h;
        if (best + qw <= bound * bound) break;  // unscanned >= s*h away
    }
    mk[(size_t)n * (P1 + P2) + (dir ? P1 : 0) + orig] = best + qw;
}

// ---------------- fallback brute-force path (r2 config) ----------------

#define BLOCK 256
#define QPT 4
#define SEG 384

__device__ __forceinline__ unsigned fkey(float f) {
    unsigned u = __float_as_uint(f);
    unsigned mask = (unsigned)((int)u >> 31) | 0x80000000u;
    return u ^ mask;
}
__device__ __forceinline__ float fdec(unsigned k) {
    unsigned mask = (k & 0x80000000u) ? 0x80000000u : 0xFFFFFFFFu;
    return __uint_as_float(k ^ mask);
}

__global__ __launch_bounds__(BLOCK) void chamfer_pass1(
    const float* __restrict__ c1, const float* __restrict__ c2,
    int P1, int P2, unsigned* __restrict__ mk_all) {
    const int z = blockIdx.z;
    const int n = z >> 1, dir = z & 1;
    const int Pq = dir ? P2 : P1;
    const int Pt = dir ? P1 : P2;
    const float* Q = (dir ? c2 : c1) + (size_t)n * Pq * 3;
    const float* T = (dir ? c1 : c2) + (size_t)n * Pt * 3;
    unsigned* mk = mk_all + (size_t)n * (P1 + P2) + (dir ? P1 : 0);

    __shared__ float4 tile[SEG];
    const int t0 = blockIdx.y * SEG;
    const int nt = Pt - t0;
    for (int j = threadIdx.x; j < SEG; j += BLOCK) {
        float4 v;
        if (j < nt) {
            const float* p = T + (size_t)(t0 + j) * 3;
            float x = p[0], y = p[1], w = p[2];
            v = make_float4(-2.f * x, -2.f * y, -2.f * w,
                            fmaf(x, x, fmaf(y, y, w * w)));
        } else {
            v = make_float4(0.f, 0.f, 0.f, INFINITY);
        }
        tile[j] = v;
    }
    __syncthreads();

    const int qbase = blockIdx.x * (BLOCK * QPT) + threadIdx.x;
    float ax[QPT], ay[QPT], az[QPT], sq[QPT], m[QPT];
    #pragma unroll
    for (int k = 0; k < QPT; ++k) {
        const int qi = qbase + k * BLOCK;
        ax[k] = 0.f; ay[k] = 0.f; az[k] = 0.f;
        if (qi < Pq) {
            const float* p = Q + (size_t)qi * 3;
            ax[k] = p[0]; ay[k] = p[1]; az[k] = p[2];
        }
        sq[k] = fmaf(ax[k], ax[k], fmaf(ay[k], ay[k], az[k] * az[k]));
        m[k] = INFINITY;
    }
    #pragma unroll 4
    for (int j = 0; j < SEG; j += 2) {
        float4 b0 = tile[j];
        float4 b1 = tile[j + 1];
        #pragma unroll
        for (int k = 0; k < QPT; ++k) {
            float d0 = fmaf(ax[k], b0.x, fmaf(ay[k], b0.y, fmaf(az[k], b0.z, b0.w)));
            float d1 = fmaf(ax[k], b1.x, fmaf(ay[k], b1.y, fmaf(az[k], b1.z, b1.w)));
            m[k] = fminf(fminf(m[k], d0), d1);
        }
    }
    #pragma unroll
    for (int k = 0; k < QPT; ++k) {
        const int qi = qbase + k * BLOCK;
        if (qi < Pq) atomicMin(&mk[qi], fkey(sq[k] + m[k]));
    }
}

__global__ __launch_bounds__(256) void pass2a_key(
    const unsigned* __restrict__ mk_all, int P1, int P2,
    float* __restrict__ partial) {
    const int z = blockIdx.y;
    const int b = blockIdx.x;
    const int n = z >> 1, dir = z & 1;
    const int Pq = dir ? P2 : P1;
    const unsigned* mk = mk_all + (size_t)n * (P1 + P2) + (dir ? P1 : 0);
    const int span = (Pq + P2A_BLOCKS - 1) / P2A_BLOCKS;
    const int lo = b * span;
    const int hi = min(lo + span, Pq);
    float s = 0.f;
    for (int q = lo + threadIdx.x; q < hi; q += 256) s += fdec(mk[q]);
    __shared__ float red[256];
    red[threadIdx.x] = s;
    __syncthreads();
    for (int off = 128; off > 0; off >>= 1) {
        if (threadIdx.x < off) red[threadIdx.x] += red[threadIdx.x + off];
        __syncthreads();
    }
    if (threadIdx.x == 0) partial[z * P2A_PAD + b] = red[0];
}

// ---------------- shared reduction ----------------

__global__ __launch_bounds__(256) void pass2a_f32(
    const float* __restrict__ mk_all, int P1, int P2,
    float* __restrict__ partial) {
    const int z = blockIdx.y;
    const int b = blockIdx.x;
    const int n = z >> 1, dir = z & 1;
    const int Pq = dir ? P2 : P1;
    const float* mk = mk_all + (size_t)n * (P1 + P2) + (dir ? P1 : 0);
    const int span = (Pq + P2A_BLOCKS - 1) / P2A_BLOCKS;
    const int lo = b * span;
    const int hi = min(lo + span, Pq);
    float s = 0.f;
    for (int q = lo + threadIdx.x; q < hi; q += 256) s += mk[q];
    __shared__ float red[256];
    red[threadIdx.x] = s;
    __syncthreads();
    for (int off = 128; off > 0; off >>= 1) {
        if (threadIdx.x < off) red[threadIdx.x] += red[threadIdx.x + off];
        __syncthreads();
    }
    if (threadIdx.x == 0) partial[z * P2A_PAD + b] = red[0];
}

__global__ void pass2b(const float* __restrict__ partial,
                       int P1, int P2, float* __restrict__ out) {
    int n = threadIdx.x;
    if (n < 2) {
        float sA = 0.f, sB = 0.f;
        for (int b = 0; b < P2A_BLOCKS; ++b) {
            sA += partial[(n * 2 + 0) * P2A_PAD + b];
            sB += partial[(n * 2 + 1) * P2A_PAD + b];
        }
        out[n] = sA / (float)P1 + sB / (float)P2;
    }
}

// ---------------- launch ----------------

static inline size_t al256(size_t x) { return (x + 255) & ~(size_t)255; }

extern "C" void kernel_launch(void* const* d_in, const int* in_sizes, int n_in,
                              void* d_out, int out_size, void* d_ws, size_t ws_size,
                              hipStream_t stream) {
    const float* c1 = (const float*)d_in[0];
    const float* c2 = (const float*)d_in[1];
    const int N = 2;
    const int P1 = in_sizes[0] / (N * 3);
    const int P2 = in_sizes[1] / (N * 3);
    const int TP = N * (P1 + P2);          // total points / mk entries
    const int Pmax = P1 > P2 ? P1 : P2;

    // ws layout (256-aligned)
    size_t o_hist = 0;
    size_t o_starts = al256(o_hist + (size_t)4 * NC * 4);
    size_t o_cellid = al256(o_starts + (size_t)4 * NC * 4);
    size_t o_rank = al256(o_cellid + (size_t)TP * 4);
    size_t o_sidx = al256(o_rank + (size_t)TP * 4);
    size_t o_mk = al256(o_sidx + (size_t)TP * 4);
    size_t o_part = al256(o_mk + (size_t)TP * 4);
    size_t o_sorted = al256(o_part + (size_t)4 * P2A_PAD * 4);
    size_t need = o_sorted + (size_t)TP * 16;

    char* ws = (char*)d_ws;
    float* partial = (float*)(ws + o_part);

    if (ws_size >= need) {
        unsigned* hist = (unsigned*)(ws + o_hist);
        unsigned* starts = (unsigned*)(ws + o_starts);
        unsigned* cellid = (unsigned*)(ws + o_cellid);
        unsigned* rank = (unsigned*)(ws + o_rank);
        unsigned* sidx = (unsigned*)(ws + o_sidx);
        float* mk = (float*)(ws + o_mk);
        float4* sorted = (float4*)(ws + o_sorted);

        hipMemsetAsync(hist, 0, (size_t)4 * NC * 4, stream);

        dim3 gb((Pmax + 255) / 256, 4);
        grid_build<<<gb, 256, 0, stream>>>(c1, c2, P1, P2, hist, cellid, rank);
        grid_scan<<<4, 1024, 0, stream>>>(hist, starts);
        grid_scatter<<<gb, 256, 0, stream>>>(c1, c2, P1, P2, starts, cellid, rank,
                                             sorted, sidx);
        dim3 gq((Pmax + QBLK - 1) / QBLK, 4);
        grid_query<<<gq, QBLK, 0, stream>>>(P1, P2, hist, starts, sorted, sidx, mk);

        dim3 g2(P2A_BLOCKS, 4);
        pass2a_f32<<<g2, 256, 0, stream>>>(mk, P1, P2, partial);
        pass2b<<<1, 64, 0, stream>>>(partial, P1, P2, (float*)d_out);
    } else {
        // fallback: brute force (r2 config)
        unsigned* mk = (unsigned*)(ws + o_mk);
        hipMemsetAsync(mk, 0xFF, (size_t)TP * 4, stream);
        dim3 g1((Pmax + BLOCK * QPT - 1) / (BLOCK * QPT),
                (Pmax + SEG - 1) / SEG, 2 * N);
        chamfer_pass1<<<g1, BLOCK, 0, stream>>>(c1, c2, P1, P2, mk);
        dim3 g2(P2A_BLOCKS, 4);
        pass2a_key<<<g2, 256, 0, stream>>>(mk, P1, P2, partial);
        pass2b<<<1, 64, 0, stream>>>(partial, P1, P2, (float*)d_out);
    }
}

// Round 5
// 186.374 us; speedup vs baseline: 2.8467x; 2.8467x over previous
//
#include <hip/hip_runtime.h>
#include <math.h>

// Chamfer distance, N=2, D=3 fp32 — grid-pruned exact NN, wave-cooperative.
// r4 post-mortem: per-lane serial cell walk = 750 waves, 1.7% VALU, latency-
// bound (516us). Fix: queries are cell-sorted, so each wave's 64 queries share
// a small cell neighborhood. Wave computes a union box (shfl min/max of cell
// coords), scans it with WAVE-UNIFORM contiguous row-ranges (cells are
// x-contiguous in the sorted array => one [start,end) per (z,y) row), 4 VALU
// per candidate serving all 64 lanes. Exactness: per-lane margin-to-box bound
// (INF at domain-clamped faces; clamp is non-expansive). Rare unsatisfied
// lanes run per-lane expanding shells from s=2 with bound (s*h)^2.
// Determinism: slot->cell map is deterministic (counting sort by cell), so
// boxes/candidate sets are deterministic; min is order-independent.
// Fallback: brute-force path if ws_size too small.

#define G 32
#define NC (G * G * G)
#define HLO -4.5f
#define HSPAN 9.0f
#define HCELL 0.28125f
#define QBLK 64
#define VCAP 100
#define P2A_BLOCKS 6
#define P2A_PAD 8

__device__ __forceinline__ int cell_coord(float x) {
    int i = (int)floorf((x - HLO) * ((float)G / HSPAN));
    return min(max(i, 0), G - 1);
}

__device__ __forceinline__ void scan_range(const float4* __restrict__ T,
                                           unsigned k, unsigned ke,
                                           float ax, float ay, float az,
                                           float& best) {
    #pragma unroll 4
    for (; k < ke; ++k) {
        float4 b = T[k];
        best = fminf(best, fmaf(ax, b.x, fmaf(ay, b.y, fmaf(az, b.z, b.w))));
    }
}

// ---------------- grid build / scan / scatter ----------------

__global__ __launch_bounds__(256) void grid_build(
    const float* __restrict__ c1, const float* __restrict__ c2,
    int P1, int P2, unsigned* __restrict__ hist,
    unsigned* __restrict__ cellid, unsigned* __restrict__ rank) {
    const int set = blockIdx.y;           // n*2 + cloud
    const int n = set >> 1, cl = set & 1;
    const int P = cl ? P2 : P1;
    const int i = blockIdx.x * 256 + threadIdx.x;
    if (i >= P) return;
    const float* p = (cl ? c2 + (size_t)n * P2 * 3 : c1 + (size_t)n * P1 * 3) + (size_t)i * 3;
    const int ix = cell_coord(p[0]), iy = cell_coord(p[1]), iz = cell_coord(p[2]);
    const unsigned c = ((unsigned)iz * G + iy) * G + ix;
    const unsigned r = atomicAdd(&hist[(size_t)set * NC + c], 1u);
    const int poff = n * (P1 + P2) + (cl ? P1 : 0);
    cellid[poff + i] = c;
    rank[poff + i] = r;
}

__global__ __launch_bounds__(1024) void grid_scan(
    const unsigned* __restrict__ hist, unsigned* __restrict__ starts) {
    const int set = blockIdx.x;
    const unsigned* h = hist + (size_t)set * NC;
    unsigned* st = starts + (size_t)set * (NC + 1);
    const int t = threadIdx.x;
    const int CH = NC / 1024;             // 32
    unsigned s = 0;
    for (int k = 0; k < CH; ++k) s += h[t * CH + k];
    __shared__ unsigned sd[1024];
    sd[t] = s;
    __syncthreads();
    for (int off = 1; off < 1024; off <<= 1) {
        unsigned v = (t >= off) ? sd[t - off] : 0u;
        __syncthreads();
        sd[t] += v;
        __syncthreads();
    }
    unsigned run = (t == 0) ? 0u : sd[t - 1];
    for (int k = 0; k < CH; ++k) {
        st[t * CH + k] = run;
        run += h[t * CH + k];
    }
    if (t == 1023) st[NC] = run;          // sentinel = total
}

__global__ __launch_bounds__(256) void grid_scatter(
    const float* __restrict__ c1, const float* __restrict__ c2,
    int P1, int P2, const unsigned* __restrict__ starts,
    const unsigned* __restrict__ cellid, const unsigned* __restrict__ rank,
    float4* __restrict__ sorted, unsigned* __restrict__ sidx) {
    const int set = blockIdx.y;
    const int n = set >> 1, cl = set & 1;
    const int P = cl ? P2 : P1;
    const int i = blockIdx.x * 256 + threadIdx.x;
    if (i >= P) return;
    const float* p = (cl ? c2 + (size_t)n * P2 * 3 : c1 + (size_t)n * P1 * 3) + (size_t)i * 3;
    const float x = p[0], y = p[1], z = p[2];
    const int poff = n * (P1 + P2) + (cl ? P1 : 0);
    const unsigned c = cellid[poff + i];
    const unsigned pos = starts[(size_t)set * (NC + 1) + c] + rank[poff + i];
    sorted[poff + pos] = make_float4(-2.f * x, -2.f * y, -2.f * z,
                                     fmaf(x, x, fmaf(y, y, z * z)));
    sidx[poff + pos] = i;
}

// ---------------- wave-cooperative query ----------------

__global__ __launch_bounds__(QBLK) void grid_query(
    int P1, int P2, const unsigned* __restrict__ starts,
    const float4* __restrict__ sorted, const unsigned* __restrict__ sidx,
    float* __restrict__ mk) {
    const int zz = blockIdx.y;            // n*2 + dir
    const int n = zz >> 1, dir = zz & 1;
    const int ts = n * 2 + (dir ? 0 : 1); // target set
    const int Pq = dir ? P2 : P1;
    const int qoff = n * (P1 + P2) + (dir ? P1 : 0);
    const int toff = n * (P1 + P2) + (dir ? 0 : P1);
    if (blockIdx.x * QBLK >= Pq) return;
    const unsigned* tst = starts + (size_t)ts * (NC + 1);
    const float4* T = sorted + toff;

    int qi = blockIdx.x * QBLK + threadIdx.x;
    const bool valid = qi < Pq;
    qi = min(qi, Pq - 1);

    const float4 q = sorted[qoff + qi];   // cell-sorted order
    const unsigned orig = sidx[qoff + qi];
    const float ax = -0.5f * q.x, ay = -0.5f * q.y, az = -0.5f * q.z, qw = q.w;
    const int cx = cell_coord(ax), cy = cell_coord(ay), cz = cell_coord(az);

    // wave-wide cell bounding box
    int bx0 = cx, bx1 = cx, by0 = cy, by1 = cy, bz0 = cz, bz1 = cz;
    #pragma unroll
    for (int o = 32; o; o >>= 1) {
        bx0 = min(bx0, __shfl_xor(bx0, o)); bx1 = max(bx1, __shfl_xor(bx1, o));
        by0 = min(by0, __shfl_xor(by0, o)); by1 = max(by1, __shfl_xor(by1, o));
        bz0 = min(bz0, __shfl_xor(bz0, o)); bz1 = max(bz1, __shfl_xor(bz1, o));
    }
    bx0 = max(bx0 - 1, 0); bx1 = min(bx1 + 1, G - 1);
    by0 = max(by0 - 1, 0); by1 = min(by1 + 1, G - 1);
    bz0 = max(bz0 - 1, 0); bz1 = min(bz1 + 1, G - 1);
    const int vol = (bx1 - bx0 + 1) * (by1 - by0 + 1) * (bz1 - bz0 + 1);

    float best = INFINITY;
    int ex0, ex1, ey0, ey1, ez0, ez1;     // scanned (effective) box

    if (vol <= VCAP) {
        // wave-uniform scan of the union box, one contiguous range per row
        for (int zc = bz0; zc <= bz1; ++zc)
            for (int yc = by0; yc <= by1; ++yc) {
                const int cbase = (zc * G + yc) * G;
                scan_range(T, tst[cbase + bx0], tst[cbase + bx1 + 1],
                           ax, ay, az, best);
            }
        ex0 = bx0; ex1 = bx1; ey0 = by0; ey1 = by1; ez0 = bz0; ez1 = bz1;
    } else {
        // per-lane own 3^3 (sparse/straddle waves: all lanes busy concurrently)
        ex0 = max(cx - 1, 0); ex1 = min(cx + 1, G - 1);
        ey0 = max(cy - 1, 0); ey1 = min(cy + 1, G - 1);
        ez0 = max(cz - 1, 0); ez1 = min(cz + 1, G - 1);
        for (int zc = ez0; zc <= ez1; ++zc)
            for (int yc = ey0; yc <= ey1; ++yc) {
                const int cbase = (zc * G + yc) * G;
                scan_range(T, tst[cbase + ex0], tst[cbase + ex1 + 1],
                           ax, ay, az, best);
            }
    }

    // margin from q to scanned-box world boundary; clamped faces are exhaustive
    // (points beyond domain are clamped into edge cells => nothing unscanned).
    float mg = INFINITY;
    if (ex0 > 0)     mg = fminf(mg, ax - (HLO + (float)ex0 * HCELL));
    if (ex1 < G - 1) mg = fminf(mg, (HLO + (float)(ex1 + 1) * HCELL) - ax);
    if (ey0 > 0)     mg = fminf(mg, ay - (HLO + (float)ey0 * HCELL));
    if (ey1 < G - 1) mg = fminf(mg, (HLO + (float)(ey1 + 1) * HCELL) - ay);
    if (ez0 > 0)     mg = fminf(mg, az - (HLO + (float)ez0 * HCELL));
    if (ez1 < G - 1) mg = fminf(mg, (HLO + (float)(ez1 + 1) * HCELL) - az);

    float d2 = qw + best;
    if (!(d2 <= mg * mg)) {
        // per-lane expanding Chebyshev shells; own 3^3 already scanned.
        for (int s = 2; s < G; ++s) {
            for (int dz = -s; dz <= s; ++dz) {
                const int z2 = cz + dz;
                if ((unsigned)z2 >= G) continue;
                const bool zf = (dz == -s) || (dz == s);
                for (int dy = -s; dy <= s; ++dy) {
                    const int y2 = cy + dy;
                    if ((unsigned)y2 >= G) continue;
                    const int cbase = (z2 * G + y2) * G;
                    if (zf || dy == -s || dy == s) {
                        const int x0 = max(cx - s, 0), x1 = min(cx + s, G - 1);
                        scan_range(T, tst[cbase + x0], tst[cbase + x1 + 1],
                                   ax, ay, az, best);
                    } else {
                        const int xl = cx - s, xh = cx + s;
                        if (xl >= 0)
                            scan_range(T, tst[cbase + xl], tst[cbase + xl + 1],
                                       ax, ay, az, best);
                        if (xh <= G - 1)
                            scan_range(T, tst[cbase + xh], tst[cbase + xh + 1],
                                       ax, ay, az, best);
                    }
                }
            }
            d2 = qw + best;
            const float bnd = (float)s * HCELL;
            if (d2 <= bnd * bnd) break;   // unscanned cells >= s*h away
        }
    }
    if (valid) mk[qoff + orig] = d2;
}

// ---------------- fallback brute-force path (r2 config) ----------------

#define BLOCK 256
#define QPT 4
#define SEG 384

__device__ __forceinline__ unsigned fkey(float f) {
    unsigned u = __float_as_uint(f);
    unsigned mask = (unsigned)((int)u >> 31) | 0x80000000u;
    return u ^ mask;
}
__device__ __forceinline__ float fdec(unsigned k) {
    unsigned mask = (k & 0x80000000u) ? 0x80000000u : 0xFFFFFFFFu;
    return __uint_as_float(k ^ mask);
}

__global__ __launch_bounds__(BLOCK) void chamfer_pass1(
    const float* __restrict__ c1, const float* __restrict__ c2,
    int P1, int P2, unsigned* __restrict__ mk_all) {
    const int z = blockIdx.z;
    const int n = z >> 1, dir = z & 1;
    const int Pq = dir ? P2 : P1;
    const int Pt = dir ? P1 : P2;
    const float* Q = (dir ? c2 : c1) + (size_t)n * Pq * 3;
    const float* T = (dir ? c1 : c2) + (size_t)n * Pt * 3;
    unsigned* mk = mk_all + (size_t)n * (P1 + P2) + (dir ? P1 : 0);

    __shared__ float4 tile[SEG];
    const int t0 = blockIdx.y * SEG;
    const int nt = Pt - t0;
    for (int j = threadIdx.x; j < SEG; j += BLOCK) {
        float4 v;
        if (j < nt) {
            const float* p = T + (size_t)(t0 + j) * 3;
            float x = p[0], y = p[1], w = p[2];
            v = make_float4(-2.f * x, -2.f * y, -2.f * w,
                            fmaf(x, x, fmaf(y, y, w * w)));
        } else {
            v = make_float4(0.f, 0.f, 0.f, INFINITY);
        }
        tile[j] = v;
    }
    __syncthreads();

    const int qbase = blockIdx.x * (BLOCK * QPT) + threadIdx.x;
    float ax[QPT], ay[QPT], az[QPT], sq[QPT], m[QPT];
    #pragma unroll
    for (int k = 0; k < QPT; ++k) {
        const int qi = qbase + k * BLOCK;
        ax[k] = 0.f; ay[k] = 0.f; az[k] = 0.f;
        if (qi < Pq) {
            const float* p = Q + (size_t)qi * 3;
            ax[k] = p[0]; ay[k] = p[1]; az[k] = p[2];
        }
        sq[k] = fmaf(ax[k], ax[k], fmaf(ay[k], ay[k], az[k] * az[k]));
        m[k] = INFINITY;
    }
    #pragma unroll 4
    for (int j = 0; j < SEG; j += 2) {
        float4 b0 = tile[j];
        float4 b1 = tile[j + 1];
        #pragma unroll
        for (int k = 0; k < QPT; ++k) {
            float d0 = fmaf(ax[k], b0.x, fmaf(ay[k], b0.y, fmaf(az[k], b0.z, b0.w)));
            float d1 = fmaf(ax[k], b1.x, fmaf(ay[k], b1.y, fmaf(az[k], b1.z, b1.w)));
            m[k] = fminf(fminf(m[k], d0), d1);
        }
    }
    #pragma unroll
    for (int k = 0; k < QPT; ++k) {
        const int qi = qbase + k * BLOCK;
        if (qi < Pq) atomicMin(&mk[qi], fkey(sq[k] + m[k]));
    }
}

__global__ __launch_bounds__(256) void pass2a_key(
    const unsigned* __restrict__ mk_all, int P1, int P2,
    float* __restrict__ partial) {
    const int z = blockIdx.y;
    const int b = blockIdx.x;
    const int n = z >> 1, dir = z & 1;
    const int Pq = dir ? P2 : P1;
    const unsigned* mk = mk_all + (size_t)n * (P1 + P2) + (dir ? P1 : 0);
    const int span = (Pq + P2A_BLOCKS - 1) / P2A_BLOCKS;
    const int lo = b * span;
    const int hi = min(lo + span, Pq);
    float s = 0.f;
    for (int q = lo + threadIdx.x; q < hi; q += 256) s += fdec(mk[q]);
    __shared__ float red[256];
    red[threadIdx.x] = s;
    __syncthreads();
    for (int off = 128; off > 0; off >>= 1) {
        if (threadIdx.x < off) red[threadIdx.x] += red[threadIdx.x + off];
        __syncthreads();
    }
    if (threadIdx.x == 0) partial[z * P2A_PAD + b] = red[0];
}

// ---------------- shared reduction ----------------

__global__ __launch_bounds__(256) void pass2a_f32(
    const float* __restrict__ mk_all, int P1, int P2,
    float* __restrict__ partial) {
    const int z = blockIdx.y;
    const int b = blockIdx.x;
    const int n = z >> 1, dir = z & 1;
    const int Pq = dir ? P2 : P1;
    const float* mk = mk_all + (size_t)n * (P1 + P2) + (dir ? P1 : 0);
    const int span = (Pq + P2A_BLOCKS - 1) / P2A_BLOCKS;
    const int lo = b * span;
    const int hi = min(lo + span, Pq);
    float s = 0.f;
    for (int q = lo + threadIdx.x; q < hi; q += 256) s += mk[q];
    __shared__ float red[256];
    red[threadIdx.x] = s;
    __syncthreads();
    for (int off = 128; off > 0; off >>= 1) {
        if (threadIdx.x < off) red[threadIdx.x] += red[threadIdx.x + off];
        __syncthreads();
    }
    if (threadIdx.x == 0) partial[z * P2A_PAD + b] = red[0];
}

__global__ void pass2b(const float* __restrict__ partial,
                       int P1, int P2, float* __restrict__ out) {
    int n = threadIdx.x;
    if (n < 2) {
        float sA = 0.f, sB = 0.f;
        for (int b = 0; b < P2A_BLOCKS; ++b) {
            sA += partial[(n * 2 + 0) * P2A_PAD + b];
            sB += partial[(n * 2 + 1) * P2A_PAD + b];
        }
        out[n] = sA / (float)P1 + sB / (float)P2;
    }
}

// ---------------- launch ----------------

static inline size_t al256(size_t x) { return (x + 255) & ~(size_t)255; }

extern "C" void kernel_launch(void* const* d_in, const int* in_sizes, int n_in,
                              void* d_out, int out_size, void* d_ws, size_t ws_size,
                              hipStream_t stream) {
    const float* c1 = (const float*)d_in[0];
    const float* c2 = (const float*)d_in[1];
    const int N = 2;
    const int P1 = in_sizes[0] / (N * 3);
    const int P2 = in_sizes[1] / (N * 3);
    const int TP = N * (P1 + P2);
    const int Pmax = P1 > P2 ? P1 : P2;

    // ws layout (256-aligned)
    size_t o_hist = 0;
    size_t o_starts = al256(o_hist + (size_t)4 * NC * 4);
    size_t o_cellid = al256(o_starts + (size_t)4 * (NC + 1) * 4);
    size_t o_rank = al256(o_cellid + (size_t)TP * 4);
    size_t o_sidx = al256(o_rank + (size_t)TP * 4);
    size_t o_mk = al256(o_sidx + (size_t)TP * 4);
    size_t o_part = al256(o_mk + (size_t)TP * 4);
    size_t o_sorted = al256(o_part + (size_t)4 * P2A_PAD * 4);
    size_t need = o_sorted + (size_t)TP * 16;

    char* ws = (char*)d_ws;
    float* partial = (float*)(ws + o_part);

    if (ws_size >= need) {
        unsigned* hist = (unsigned*)(ws + o_hist);
        unsigned* starts = (unsigned*)(ws + o_starts);
        unsigned* cellid = (unsigned*)(ws + o_cellid);
        unsigned* rank = (unsigned*)(ws + o_rank);
        unsigned* sidx = (unsigned*)(ws + o_sidx);
        float* mk = (float*)(ws + o_mk);
        float4* sorted = (float4*)(ws + o_sorted);

        hipMemsetAsync(hist, 0, (size_t)4 * NC * 4, stream);

        dim3 gb((Pmax + 255) / 256, 4);
        grid_build<<<gb, 256, 0, stream>>>(c1, c2, P1, P2, hist, cellid, rank);
        grid_scan<<<4, 1024, 0, stream>>>(hist, starts);
        grid_scatter<<<gb, 256, 0, stream>>>(c1, c2, P1, P2, starts, cellid, rank,
                                             sorted, sidx);
        dim3 gq((Pmax + QBLK - 1) / QBLK, 4);
        grid_query<<<gq, QBLK, 0, stream>>>(P1, P2, starts, sorted, sidx, mk);

        dim3 g2(P2A_BLOCKS, 4);
        pass2a_f32<<<g2, 256, 0, stream>>>(mk, P1, P2, partial);
        pass2b<<<1, 64, 0, stream>>>(partial, P1, P2, (float*)d_out);
    } else {
        // fallback: brute force (r2 config)
        unsigned* mk = (unsigned*)(ws + o_mk);
        hipMemsetAsync(mk, 0xFF, (size_t)TP * 4, stream);
        dim3 g1((Pmax + BLOCK * QPT - 1) / (BLOCK * QPT),
                (Pmax + SEG - 1) / SEG, 2 * N);
        chamfer_pass1<<<g1, BLOCK, 0, stream>>>(c1, c2, P1, P2, mk);
        dim3 g2(P2A_BLOCKS, 4);
        pass2a_key<<<g2, 256, 0, stream>>>(mk, P1, P2, partial);
        pass2b<<<1, 64, 0, stream>>>(partial, P1, P2, (float*)d_out);
    }
}